// Round 12
// baseline (461.667 us; speedup 1.0000x reference)
//
#include <hip/hip_runtime.h>
#include <math.h>

#define N_NODES 100000
#define N_EDGES 1600000
#define INDIM 128
#define F 64
#define ODIM 10
#define NG 512
#define NB_SCAN ((N_NODES + 255) / 256)  // 391
#define PSZ 12500                        // dst-partition size (N_NODES/8)
#define BIN_BLOCKS 2048                  // 8 groups x 256 blocks

typedef unsigned short ushort_t;
typedef unsigned int uint_t;
typedef unsigned long long ull_t;
typedef __attribute__((ext_vector_type(8))) short bf16x8;
typedef __attribute__((ext_vector_type(4))) float f32x4;

__device__ inline ushort_t f2b(float f) {           // fp32 -> bf16 RNE
    uint_t u = __float_as_uint(f);
    u += 0x7FFF + ((u >> 16) & 1);
    return (ushort_t)(u >> 16);
}
__device__ inline float b2f(ushort_t u) {           // bf16 -> fp32 exact
    return __uint_as_float(((uint_t)u) << 16);
}

// ---------------- utility ----------------
__global__ void zero_kernel(float* p, int n) {
    int i = blockIdx.x * blockDim.x + threadIdx.x;
    if (i < n) p[i] = 0.0f;
}

__global__ void deg_kernel(const int* __restrict__ dst, int* __restrict__ deg) {
    int e = blockIdx.x * blockDim.x + threadIdx.x;
    if (e < N_EDGES) atomicAdd(&deg[dst[e]], 1);
}

__global__ void dinv_kernel(const int* __restrict__ deg, float* __restrict__ dinv) {
    int i = blockIdx.x * blockDim.x + threadIdx.x;
    if (i < N_NODES) dinv[i] = rsqrtf((float)deg[i] + 1.0f);  // +1 self-loop
}

// batch SORTED -> per-graph [start,end) via binary search; also emit gstart for pooling
__global__ void cnt_bs_kernel(const int* __restrict__ batch, float* __restrict__ cnt,
                              int* __restrict__ gstart) {
    int g = blockIdx.x * blockDim.x + threadIdx.x;
    if (g >= NG) return;
    int lo = 0, hi = N_NODES;
    while (lo < hi) { int mid = (lo + hi) >> 1; if (batch[mid] < g) lo = mid + 1; else hi = mid; }
    int start = lo;
    lo = 0; hi = N_NODES;
    while (lo < hi) { int mid = (lo + hi) >> 1; if (batch[mid] <= g) lo = mid + 1; else hi = mid; }
    cnt[g] = (float)(lo - start);
    gstart[g] = start;
    if (g == 0) gstart[NG] = N_NODES;
}

// ---------------- CSR build ----------------
__global__ void scan1_kernel(const int* __restrict__ deg, int* __restrict__ rp,
                             int* __restrict__ bsum) {
    int i = blockIdx.x * 256 + threadIdx.x;
    int v = (i < N_NODES) ? deg[i] : 0;
    int lane = threadIdx.x & 63, w = threadIdx.x >> 6;
    int x = v;
#pragma unroll
    for (int off = 1; off < 64; off <<= 1) {
        int y = __shfl_up(x, off, 64);
        if (lane >= off) x += y;
    }
    __shared__ int wsum[4];
    if (lane == 63) wsum[w] = x;
    __syncthreads();
    int add = 0;
    for (int j = 0; j < w; ++j) add += wsum[j];
    if (i < N_NODES) rp[i] = x - v + add;
    if (threadIdx.x == 255) bsum[blockIdx.x] = x + add;
}

__global__ void scan2_kernel(int* __restrict__ bsum) {
    int i = threadIdx.x;
    int v = (i < NB_SCAN) ? bsum[i] : 0;
    int lane = i & 63, w = i >> 6;
    int x = v;
#pragma unroll
    for (int off = 1; off < 64; off <<= 1) {
        int y = __shfl_up(x, off, 64);
        if (lane >= off) x += y;
    }
    __shared__ int wsum[8];
    if (lane == 63) wsum[w] = x;
    __syncthreads();
    int add = 0;
    for (int j = 0; j < w; ++j) add += wsum[j];
    if (i < NB_SCAN) bsum[i] = x - v + add;
}

__global__ void scan3_kernel(int* __restrict__ rp, const int* __restrict__ bsum,
                             int* __restrict__ cursor) {
    int i = blockIdx.x * 256 + threadIdx.x;
    if (i < N_NODES) {
        int v = rp[i] + bsum[blockIdx.x];
        rp[i] = v;
        cursor[i] = v;
    }
    if (i == 0) rp[N_NODES] = N_EDGES;
}

// Round-8-proven single-pass partitioned binning (plain loads — NT loads were a
// measured regression in round 9). 4B meta payload; NT STORE on the scatter to
// sidestep L2 write-allocate on partial lines.
__global__ void bin_part_kernel(const int* __restrict__ src, const int* __restrict__ dst,
                                int* __restrict__ cursor, int* __restrict__ meta_src) {
    int grp = blockIdx.x & 7;
    int gidx = blockIdx.x >> 3;
    int lo = grp * PSZ, hi = lo + PSZ;
    const int stride = (BIN_BLOCKS / 8) * 256;
    for (int e = gidx * 256 + threadIdx.x; e < N_EDGES; e += stride) {
        int d = dst[e];
        if (d < lo || d >= hi) continue;
        int s = src[e];
        int pos = atomicAdd(&cursor[d], 1);
        __builtin_nontemporal_store(s, &meta_src[pos]);
    }
}

// ---------------- packing ----------------
// W [K,64] fp32 -> packed bf16: Wp[((s*4+g)*64 + n)*8 + j] = W[(s*32 + g*8 + j)*64 + n]
template <int K>
__global__ void packW_kernel(const float* __restrict__ W, ushort_t* __restrict__ Wp) {
    int i = blockIdx.x * 256 + threadIdx.x;
    if (i >= K * 64) return;
    int k = i >> 6, n = i & 63;
    int s = k >> 5, g = (k >> 3) & 3, j = k & 7;
    Wp[(((s * 4 + g) * 64) + n) * 8 + j] = f2b(W[i]);
}

// ---------------- GEMM via MFMA: h = X @ W  (bf16 or fp32 A, bf16 out, fp32 accum) ----------------
template <int K, bool A32>
__global__ void __launch_bounds__(256) gemm_mfma_kernel(const void* __restrict__ Xp,
                                                        const ushort_t* __restrict__ Wp,
                                                        ushort_t* __restrict__ h) {
    int lane = threadIdx.x & 63;
    int wv = threadIdx.x >> 6;
    int r = lane & 15, g = lane >> 4;
    int row0 = blockIdx.x * 64 + wv * 16;
    int arow = row0 + r;
    if (arow >= N_NODES) arow = N_NODES - 1;
    f32x4 acc0 = {0, 0, 0, 0}, acc1 = {0, 0, 0, 0}, acc2 = {0, 0, 0, 0}, acc3 = {0, 0, 0, 0};
#pragma unroll
    for (int s = 0; s < K / 32; ++s) {
        bf16x8 a;
        if constexpr (A32) {
            const float* xrow = (const float*)Xp + (long long)arow * K + g * 8 + s * 32;
            float4 xa = *(const float4*)xrow;
            float4 xb = *(const float4*)(xrow + 4);
            a[0] = (short)f2b(xa.x); a[1] = (short)f2b(xa.y);
            a[2] = (short)f2b(xa.z); a[3] = (short)f2b(xa.w);
            a[4] = (short)f2b(xb.x); a[5] = (short)f2b(xb.y);
            a[6] = (short)f2b(xb.z); a[7] = (short)f2b(xb.w);
        } else {
            const ushort_t* xrow = (const ushort_t*)Xp + (long long)arow * K + g * 8 + s * 32;
            a = *(const bf16x8*)xrow;
        }
        const ushort_t* wb = Wp + (((s * 4 + g) * 64) + r) * 8;
        bf16x8 b0 = *(const bf16x8*)(wb + 0 * 128);
        bf16x8 b1 = *(const bf16x8*)(wb + 1 * 128);
        bf16x8 b2 = *(const bf16x8*)(wb + 2 * 128);
        bf16x8 b3 = *(const bf16x8*)(wb + 3 * 128);
        acc0 = __builtin_amdgcn_mfma_f32_16x16x32_bf16(a, b0, acc0, 0, 0, 0);
        acc1 = __builtin_amdgcn_mfma_f32_16x16x32_bf16(a, b1, acc1, 0, 0, 0);
        acc2 = __builtin_amdgcn_mfma_f32_16x16x32_bf16(a, b2, acc2, 0, 0, 0);
        acc3 = __builtin_amdgcn_mfma_f32_16x16x32_bf16(a, b3, acc3, 0, 0, 0);
    }
#pragma unroll
    for (int q = 0; q < 4; ++q) {
        int rr = row0 + g * 4 + q;
        if (rr < N_NODES) {
            ushort_t* hp = h + (long long)rr * 64 + r;
            hp[0]  = f2b(acc0[q]);
            hp[16] = f2b(acc1[q]);
            hp[32] = f2b(acc2[q]);
            hp[48] = f2b(acc3[q]);
        }
    }
}

// ---------------- fused: selfloop+bias + CSR-gather (bf16) + ReLU ----------------
// 32-deep gather batching: 8KB in flight per wave (Little's-law fix for the
// 1.7 vs 3.5 TB/s fabric gap measured in round 8).
__global__ void aggregate_kernel(const ushort_t* __restrict__ h, const int* __restrict__ meta_src,
                                 const int* __restrict__ rp, const float* __restrict__ dinv,
                                 const float* __restrict__ b, ushort_t* __restrict__ xout) {
    int node = blockIdx.x * 4 + (threadIdx.x >> 6);
    int f = threadIdx.x & 63;
    float di = dinv[node];
    float acc = b[f] + di * di * b2f(h[(long long)node * F + f]);
    int e = rp[node], end = rp[node + 1];
    while (e < end) {
        int cnt = end - e;
        if (cnt > 64) cnt = 64;
        int ms = 0;
        float mw = 0.0f;
        if (f < cnt) {
            ms = __builtin_nontemporal_load(&meta_src[e + f]);
            mw = dinv[ms] * di;
        }
        int j = 0;
        for (; j + 32 <= cnt; j += 32) {
            ushort_t hv[32];
#pragma unroll
            for (int c = 0; c < 32; ++c) {
                int s = __shfl(ms, j + c, 64);
                hv[c] = h[(long long)s * F + f];
            }
#pragma unroll
            for (int c = 0; c < 32; ++c) {
                float wv = __shfl(mw, j + c, 64);
                acc = fmaf(wv, b2f(hv[c]), acc);
            }
        }
        for (; j + 8 <= cnt; j += 8) {
            ushort_t hv[8];
#pragma unroll
            for (int c = 0; c < 8; ++c) {
                int s = __shfl(ms, j + c, 64);
                hv[c] = h[(long long)s * F + f];
            }
#pragma unroll
            for (int c = 0; c < 8; ++c) {
                float wv = __shfl(mw, j + c, 64);
                acc = fmaf(wv, b2f(hv[c]), acc);
            }
        }
        for (; j < cnt; ++j) {
            int s = __shfl(ms, j, 64);
            float wv = __shfl(mw, j, 64);
            acc = fmaf(wv, b2f(h[(long long)s * F + f]), acc);
        }
        e += cnt;
    }
    float v = fmaxf(acc, 0.0f);
    xout[(long long)node * F + f] = f2b(v);
}

// ---------------- segmented pool: block g sums X rows gstart[g]..gstart[g+1] ----------------
__global__ void pool_kernel(const ushort_t* __restrict__ X, const int* __restrict__ gstart,
                            float* __restrict__ sums) {
    int g = blockIdx.x;
    int f = threadIdx.x & 63;
    int w = threadIdx.x >> 6;
    int n0 = gstart[g], n1 = gstart[g + 1];
    float s = 0.0f;
    for (int n = n0 + w; n < n1; n += 4)
        s += b2f(X[(long long)n * F + f]);
    __shared__ float red[4][64];
    red[w][f] = s;
    __syncthreads();
    if (w == 0)
        sums[g * F + f] = red[0][f] + red[1][f] + red[2][f] + red[3][f];
}

// ---------------- head + final ----------------
__global__ void head_kernel(const float* __restrict__ sums, const float* __restrict__ cnt,
                            const float* __restrict__ Wl1, const float* __restrict__ bl1,
                            const float* __restrict__ Wl2, const float* __restrict__ bl2,
                            const float* __restrict__ Wl3, const float* __restrict__ bl3,
                            float* __restrict__ gcat) {
    int g = blockIdx.x;
    int t = threadIdx.x;
    if (t >= 30) return;
    int l = t / 10, c = t % 10;
    const float* Wl = (l == 0) ? Wl1 : (l == 1) ? Wl2 : Wl3;
    const float* bl = (l == 0) ? bl1 : (l == 1) ? bl2 : bl3;
    float invc = 1.0f / fmaxf(cnt[g], 1.0f);
    const float* srow = sums + (long long)l * NG * F + (long long)g * F;
    float acc = bl[c];
    for (int k = 0; k < F; ++k) acc += srow[k] * invc * Wl[k * ODIM + c];
    gcat[g * 30 + t] = acc;
}

__global__ void final_kernel(const float* __restrict__ gcat, const float* __restrict__ Wf,
                             const float* __restrict__ bf, float* __restrict__ out) {
    int g = blockIdx.x * blockDim.x + threadIdx.x;
    if (g >= NG) return;
    float z[ODIM];
    float m = -1e30f;
    for (int c = 0; c < ODIM; ++c) {
        float acc = bf[c];
        for (int k = 0; k < 30; ++k) acc += gcat[g * 30 + k] * Wf[k * ODIM + c];
        z[c] = acc;
        m = fmaxf(m, acc);
    }
    float s = 0.0f;
    for (int c = 0; c < ODIM; ++c) { z[c] = expf(z[c] - m); s += z[c]; }
    float inv = 1.0f / s;
    for (int c = 0; c < ODIM; ++c) out[g * ODIM + c] = z[c] * inv;
}

extern "C" void kernel_launch(void* const* d_in, const int* in_sizes, int n_in,
                              void* d_out, int out_size, void* d_ws, size_t ws_size,
                              hipStream_t stream) {
    const float* features = (const float*)d_in[0];
    const int*   edge     = (const int*)d_in[1];
    const int*   batch    = (const int*)d_in[2];
    const float* W1 = (const float*)d_in[3];
    const float* b1 = (const float*)d_in[4];
    const float* W2 = (const float*)d_in[5];
    const float* b2 = (const float*)d_in[6];
    const float* W3 = (const float*)d_in[7];
    const float* b3 = (const float*)d_in[8];
    const float* Wl1 = (const float*)d_in[9];
    const float* bl1 = (const float*)d_in[10];
    const float* Wl2 = (const float*)d_in[11];
    const float* bl2 = (const float*)d_in[12];
    const float* Wl3 = (const float*)d_in[13];
    const float* bl3 = (const float*)d_in[14];
    const float* Wf = (const float*)d_in[15];
    const float* bf = (const float*)d_in[16];

    const int* src = edge;
    const int* dst = edge + N_EDGES;

    // ---- workspace layout (256B-aligned slabs) ----
    char* p = (char*)d_ws;
    auto alloc = [&](size_t bytes) -> char* {
        char* q = p;
        p += (bytes + 255) & ~(size_t)255;
        return q;
    };
    int*      deg    = (int*)alloc(N_NODES * 4);
    char*     zend   = p;
    float*    sums   = (float*)alloc(3 * NG * F * 4);
    float*    cnt    = (float*)alloc(NG * 4);
    float*    dinv   = (float*)alloc(N_NODES * 4);
    int*      rp     = (int*)alloc((N_NODES + 1) * 4);
    int*      cursor = (int*)alloc(N_NODES * 4);
    int*      bsum   = (int*)alloc(512 * 4);
    int*      gstart = (int*)alloc((NG + 1) * 4);
    float*    gcat   = (float*)alloc(NG * 30 * 4);
    ushort_t* X      = (ushort_t*)alloc((size_t)N_NODES * F * 2);
    ushort_t* H      = (ushort_t*)alloc((size_t)N_NODES * F * 2);
    int*      meta   = (int*)alloc((size_t)N_EDGES * 4);
    ushort_t* Wp1    = (ushort_t*)alloc(INDIM * 64 * 2);
    ushort_t* Wp2    = (ushort_t*)alloc(F * 64 * 2);
    ushort_t* Wp3    = (ushort_t*)alloc(F * 64 * 2);

    const int zeroN = (int)((zend - (char*)deg) / 4);
    hipLaunchKernelGGL(zero_kernel, dim3((zeroN + 255) / 256), dim3(256), 0, stream, (float*)deg, zeroN);
    hipLaunchKernelGGL(deg_kernel, dim3((N_EDGES + 255) / 256), dim3(256), 0, stream, dst, deg);
    hipLaunchKernelGGL(dinv_kernel, dim3((N_NODES + 255) / 256), dim3(256), 0, stream, deg, dinv);
    hipLaunchKernelGGL(cnt_bs_kernel, dim3((NG + 255) / 256), dim3(256), 0, stream, batch, cnt, gstart);
    hipLaunchKernelGGL(scan1_kernel, dim3(NB_SCAN), dim3(256), 0, stream, deg, rp, bsum);
    hipLaunchKernelGGL(scan2_kernel, dim3(1), dim3(512), 0, stream, bsum);
    hipLaunchKernelGGL(scan3_kernel, dim3(NB_SCAN), dim3(256), 0, stream, rp, bsum, cursor);
    hipLaunchKernelGGL(bin_part_kernel, dim3(BIN_BLOCKS), dim3(256), 0, stream, src, dst, cursor, meta);

    // W packs
    hipLaunchKernelGGL((packW_kernel<INDIM>), dim3((INDIM * 64 + 255) / 256), dim3(256), 0, stream, W1, Wp1);
    hipLaunchKernelGGL((packW_kernel<F>), dim3((F * 64 + 255) / 256), dim3(256), 0, stream, W2, Wp2);
    hipLaunchKernelGGL((packW_kernel<F>), dim3((F * 64 + 255) / 256), dim3(256), 0, stream, W3, Wp3);

    const int nodeBlocks = N_NODES / 4;          // 25000 (aggregate)
    const int gemmBlocks = (N_NODES + 63) / 64;  // 1563

    // ---- layer 1 (fp32 A read + in-register bf16 convert) ----
    hipLaunchKernelGGL((gemm_mfma_kernel<INDIM, true>), dim3(gemmBlocks), dim3(256), 0, stream, (const void*)features, Wp1, H);
    hipLaunchKernelGGL(aggregate_kernel, dim3(nodeBlocks), dim3(256), 0, stream, H, meta, rp, dinv, b1, X);
    hipLaunchKernelGGL(pool_kernel, dim3(NG), dim3(256), 0, stream, X, gstart, sums + 0 * NG * F);
    // ---- layer 2 ----
    hipLaunchKernelGGL((gemm_mfma_kernel<F, false>), dim3(gemmBlocks), dim3(256), 0, stream, (const void*)X, Wp2, H);
    hipLaunchKernelGGL(aggregate_kernel, dim3(nodeBlocks), dim3(256), 0, stream, H, meta, rp, dinv, b2, X);
    hipLaunchKernelGGL(pool_kernel, dim3(NG), dim3(256), 0, stream, X, gstart, sums + 1 * NG * F);
    // ---- layer 3 ----
    hipLaunchKernelGGL((gemm_mfma_kernel<F, false>), dim3(gemmBlocks), dim3(256), 0, stream, (const void*)X, Wp3, H);
    hipLaunchKernelGGL(aggregate_kernel, dim3(nodeBlocks), dim3(256), 0, stream, H, meta, rp, dinv, b3, X);
    hipLaunchKernelGGL(pool_kernel, dim3(NG), dim3(256), 0, stream, X, gstart, sums + 2 * NG * F);

    // ---- heads + final ----
    hipLaunchKernelGGL(head_kernel, dim3(NG), dim3(32), 0, stream, sums, cnt,
                       Wl1, bl1, Wl2, bl2, Wl3, bl3, gcat);
    hipLaunchKernelGGL(final_kernel, dim3((NG + 255) / 256), dim3(256), 0, stream, gcat, Wf, bf, (float*)d_out);
}

// Round 13
// 400.768 us; speedup vs baseline: 1.1520x; 1.1520x over previous
//
#include <hip/hip_runtime.h>
#include <math.h>

#define N_NODES 100000
#define N_EDGES 1600000
#define INDIM 128
#define F 64
#define ODIM 10
#define NG 512
#define NB_SCAN ((N_NODES + 255) / 256)  // 391
#define PSZ 12500                        // dst-partition size (N_NODES/8)
#define BIN_BLOCKS 2048                  // 8 groups x 256 blocks
#define NPB 16                           // nodes per aggregate block
#define ECAP 2048                        // LDS edge capacity per block (mean 256)

typedef unsigned short ushort_t;
typedef unsigned int uint_t;
typedef unsigned long long ull_t;
typedef __attribute__((ext_vector_type(8))) short bf16x8;
typedef __attribute__((ext_vector_type(4))) float f32x4;

__device__ inline ushort_t f2b(float f) {           // fp32 -> bf16 RNE
    uint_t u = __float_as_uint(f);
    u += 0x7FFF + ((u >> 16) & 1);
    return (ushort_t)(u >> 16);
}
__device__ inline float b2f(ushort_t u) {           // bf16 -> fp32 exact
    return __uint_as_float(((uint_t)u) << 16);
}

// ---------------- utility ----------------
__global__ void zero_kernel(float* p, int n) {
    int i = blockIdx.x * blockDim.x + threadIdx.x;
    if (i < n) p[i] = 0.0f;
}

__global__ void deg_kernel(const int* __restrict__ dst, int* __restrict__ deg) {
    int e = blockIdx.x * blockDim.x + threadIdx.x;
    if (e < N_EDGES) atomicAdd(&deg[__builtin_nontemporal_load(&dst[e])], 1);
}

__global__ void dinv_kernel(const int* __restrict__ deg, float* __restrict__ dinv) {
    int i = blockIdx.x * blockDim.x + threadIdx.x;
    if (i < N_NODES) dinv[i] = rsqrtf((float)deg[i] + 1.0f);  // +1 self-loop
}

// batch SORTED -> per-graph [start,end) via binary search; also emit gstart for pooling
__global__ void cnt_bs_kernel(const int* __restrict__ batch, float* __restrict__ cnt,
                              int* __restrict__ gstart) {
    int g = blockIdx.x * blockDim.x + threadIdx.x;
    if (g >= NG) return;
    int lo = 0, hi = N_NODES;
    while (lo < hi) { int mid = (lo + hi) >> 1; if (batch[mid] < g) lo = mid + 1; else hi = mid; }
    int start = lo;
    lo = 0; hi = N_NODES;
    while (lo < hi) { int mid = (lo + hi) >> 1; if (batch[mid] <= g) lo = mid + 1; else hi = mid; }
    cnt[g] = (float)(lo - start);
    gstart[g] = start;
    if (g == 0) gstart[NG] = N_NODES;
}

// ---------------- CSR build ----------------
__global__ void scan1_kernel(const int* __restrict__ deg, int* __restrict__ rp,
                             int* __restrict__ bsum) {
    int i = blockIdx.x * 256 + threadIdx.x;
    int v = (i < N_NODES) ? deg[i] : 0;
    int lane = threadIdx.x & 63, w = threadIdx.x >> 6;
    int x = v;
#pragma unroll
    for (int off = 1; off < 64; off <<= 1) {
        int y = __shfl_up(x, off, 64);
        if (lane >= off) x += y;
    }
    __shared__ int wsum[4];
    if (lane == 63) wsum[w] = x;
    __syncthreads();
    int add = 0;
    for (int j = 0; j < w; ++j) add += wsum[j];
    if (i < N_NODES) rp[i] = x - v + add;
    if (threadIdx.x == 255) bsum[blockIdx.x] = x + add;
}

__global__ void scan2_kernel(int* __restrict__ bsum) {
    int i = threadIdx.x;
    int v = (i < NB_SCAN) ? bsum[i] : 0;
    int lane = i & 63, w = i >> 6;
    int x = v;
#pragma unroll
    for (int off = 1; off < 64; off <<= 1) {
        int y = __shfl_up(x, off, 64);
        if (lane >= off) x += y;
    }
    __shared__ int wsum[8];
    if (lane == 63) wsum[w] = x;
    __syncthreads();
    int add = 0;
    for (int j = 0; j < w; ++j) add += wsum[j];
    if (i < NB_SCAN) bsum[i] = x - v + add;
}

__global__ void scan3_kernel(int* __restrict__ rp, const int* __restrict__ bsum,
                             int* __restrict__ cursor) {
    int i = blockIdx.x * 256 + threadIdx.x;
    if (i < N_NODES) {
        int v = rp[i] + bsum[blockIdx.x];
        rp[i] = v;
        cursor[i] = v;
    }
    if (i == 0) rp[N_NODES] = N_EDGES;
}

// Single-pass partitioned binning, plain loads + plain 4B store (best measured).
__global__ void bin_part_kernel(const int* __restrict__ src, const int* __restrict__ dst,
                                int* __restrict__ cursor, int* __restrict__ meta_src) {
    int grp = blockIdx.x & 7;
    int gidx = blockIdx.x >> 3;
    int lo = grp * PSZ, hi = lo + PSZ;
    const int stride = (BIN_BLOCKS / 8) * 256;
    for (int e = gidx * 256 + threadIdx.x; e < N_EDGES; e += stride) {
        int d = dst[e];
        if (d < lo || d >= hi) continue;
        int s = src[e];
        int pos = atomicAdd(&cursor[d], 1);
        meta_src[pos] = s;
    }
}

// ---------------- packing ----------------
template <int K>
__global__ void packW_kernel(const float* __restrict__ W, ushort_t* __restrict__ Wp) {
    int i = blockIdx.x * 256 + threadIdx.x;
    if (i >= K * 64) return;
    int k = i >> 6, n = i & 63;
    int s = k >> 5, g = (k >> 3) & 3, j = k & 7;
    Wp[(((s * 4 + g) * 64) + n) * 8 + j] = f2b(W[i]);
}

// ---------------- GEMM via MFMA ----------------
template <int K, bool A32>
__global__ void __launch_bounds__(256) gemm_mfma_kernel(const void* __restrict__ Xp,
                                                        const ushort_t* __restrict__ Wp,
                                                        ushort_t* __restrict__ h) {
    int lane = threadIdx.x & 63;
    int wv = threadIdx.x >> 6;
    int r = lane & 15, g = lane >> 4;
    int row0 = blockIdx.x * 64 + wv * 16;
    int arow = row0 + r;
    if (arow >= N_NODES) arow = N_NODES - 1;
    f32x4 acc0 = {0, 0, 0, 0}, acc1 = {0, 0, 0, 0}, acc2 = {0, 0, 0, 0}, acc3 = {0, 0, 0, 0};
#pragma unroll
    for (int s = 0; s < K / 32; ++s) {
        bf16x8 a;
        if constexpr (A32) {
            const float* xrow = (const float*)Xp + (long long)arow * K + g * 8 + s * 32;
            float4 xa = *(const float4*)xrow;
            float4 xb = *(const float4*)(xrow + 4);
            a[0] = (short)f2b(xa.x); a[1] = (short)f2b(xa.y);
            a[2] = (short)f2b(xa.z); a[3] = (short)f2b(xa.w);
            a[4] = (short)f2b(xb.x); a[5] = (short)f2b(xb.y);
            a[6] = (short)f2b(xb.z); a[7] = (short)f2b(xb.w);
        } else {
            const ushort_t* xrow = (const ushort_t*)Xp + (long long)arow * K + g * 8 + s * 32;
            a = *(const bf16x8*)xrow;
        }
        const ushort_t* wb = Wp + (((s * 4 + g) * 64) + r) * 8;
        bf16x8 b0 = *(const bf16x8*)(wb + 0 * 128);
        bf16x8 b1 = *(const bf16x8*)(wb + 1 * 128);
        bf16x8 b2 = *(const bf16x8*)(wb + 2 * 128);
        bf16x8 b3 = *(const bf16x8*)(wb + 3 * 128);
        acc0 = __builtin_amdgcn_mfma_f32_16x16x32_bf16(a, b0, acc0, 0, 0, 0);
        acc1 = __builtin_amdgcn_mfma_f32_16x16x32_bf16(a, b1, acc1, 0, 0, 0);
        acc2 = __builtin_amdgcn_mfma_f32_16x16x32_bf16(a, b2, acc2, 0, 0, 0);
        acc3 = __builtin_amdgcn_mfma_f32_16x16x32_bf16(a, b3, acc3, 0, 0, 0);
    }
#pragma unroll
    for (int q = 0; q < 4; ++q) {
        int rr = row0 + g * 4 + q;
        if (rr < N_NODES) {
            ushort_t* hp = h + (long long)rr * 64 + r;
            hp[0]  = f2b(acc0[q]);
            hp[16] = f2b(acc1[q]);
            hp[32] = f2b(acc2[q]);
            hp[48] = f2b(acc3[q]);
        }
    }
}

// ---------------- fused aggregate: LDS-staged meta (CSR contiguity) ----------------
// 16 consecutive nodes/block -> their meta is one contiguous slab. Phase 1:
// coalesced load of all edges + weight precompute into LDS. Phase 2: waves
// consume from LDS (no global meta latency), gather batches of 8 (24 VGPR).
__global__ void __launch_bounds__(256) aggregate_kernel(
        const ushort_t* __restrict__ h, const int* __restrict__ meta_src,
        const int* __restrict__ rp, const float* __restrict__ dinv,
        const float* __restrict__ b, ushort_t* __restrict__ xout) {
    __shared__ int   lsrc[ECAP];
    __shared__ float lw[ECAP];
    __shared__ int   lrp[NPB + 1];
    int tid = threadIdx.x;
    int n0 = blockIdx.x * NPB;
    if (tid < NPB + 1) lrp[tid] = rp[n0 + tid];
    __syncthreads();
    int e0 = lrp[0];
    int span = lrp[NPB] - e0;
    if (span > ECAP) span = ECAP;
    for (int i = tid; i < span; i += 256) {
        int s = meta_src[e0 + i];
        int idx = e0 + i;
        int n = 0;
#pragma unroll
        for (int k = 1; k < NPB; ++k) n += (idx >= lrp[k]);
        lsrc[i] = s;
        lw[i] = dinv[s] * dinv[n0 + n];
    }
    __syncthreads();

    int wv = tid >> 6, f = tid & 63;
    for (int q = 0; q < 4; ++q) {
        int node = n0 + wv * 4 + q;
        float di = dinv[node];
        float acc = b[f] + di * di * b2f(h[(long long)node * F + f]);
        int eb = lrp[wv * 4 + q] - e0;
        int ee = lrp[wv * 4 + q + 1] - e0;
        int ebL = (eb < span) ? eb : span;
        int eeL = (ee < span) ? ee : span;
        for (int j = ebL; j < eeL; j += 8) {
            int si[8]; float wi[8]; ushort_t hv[8];
#pragma unroll
            for (int c = 0; c < 8; ++c) {
                int idx = j + c;
                bool ok = idx < eeL;
                int ii = ok ? idx : ebL;
                si[c] = lsrc[ii];
                wi[c] = ok ? lw[ii] : 0.0f;
            }
#pragma unroll
            for (int c = 0; c < 8; ++c) hv[c] = h[(long long)si[c] * F + f];
#pragma unroll
            for (int c = 0; c < 8; ++c) acc = fmaf(wi[c], b2f(hv[c]), acc);
        }
        // overflow fallback (block edge-span > ECAP; essentially never)
        for (int i = (eb > span ? eb : span); i < ee; ++i) {
            int s = meta_src[e0 + i];
            float w = dinv[s] * di;
            acc = fmaf(w, b2f(h[(long long)s * F + f]), acc);
        }
        float v = fmaxf(acc, 0.0f);
        xout[(long long)node * F + f] = f2b(v);
    }
}

// ---------------- segmented pool ----------------
__global__ void pool_kernel(const ushort_t* __restrict__ X, const int* __restrict__ gstart,
                            float* __restrict__ sums) {
    int g = blockIdx.x;
    int f = threadIdx.x & 63;
    int w = threadIdx.x >> 6;
    int n0 = gstart[g], n1 = gstart[g + 1];
    float s = 0.0f;
    for (int n = n0 + w; n < n1; n += 4)
        s += b2f(X[(long long)n * F + f]);
    __shared__ float red[4][64];
    red[w][f] = s;
    __syncthreads();
    if (w == 0)
        sums[g * F + f] = red[0][f] + red[1][f] + red[2][f] + red[3][f];
}

// ---------------- head + final ----------------
__global__ void head_kernel(const float* __restrict__ sums, const float* __restrict__ cnt,
                            const float* __restrict__ Wl1, const float* __restrict__ bl1,
                            const float* __restrict__ Wl2, const float* __restrict__ bl2,
                            const float* __restrict__ Wl3, const float* __restrict__ bl3,
                            float* __restrict__ gcat) {
    int g = blockIdx.x;
    int t = threadIdx.x;
    if (t >= 30) return;
    int l = t / 10, c = t % 10;
    const float* Wl = (l == 0) ? Wl1 : (l == 1) ? Wl2 : Wl3;
    const float* bl = (l == 0) ? bl1 : (l == 1) ? bl2 : bl3;
    float invc = 1.0f / fmaxf(cnt[g], 1.0f);
    const float* srow = sums + (long long)l * NG * F + (long long)g * F;
    float acc = bl[c];
    for (int k = 0; k < F; ++k) acc += srow[k] * invc * Wl[k * ODIM + c];
    gcat[g * 30 + t] = acc;
}

__global__ void final_kernel(const float* __restrict__ gcat, const float* __restrict__ Wf,
                             const float* __restrict__ bf, float* __restrict__ out) {
    int g = blockIdx.x * blockDim.x + threadIdx.x;
    if (g >= NG) return;
    float z[ODIM];
    float m = -1e30f;
    for (int c = 0; c < ODIM; ++c) {
        float acc = bf[c];
        for (int k = 0; k < 30; ++k) acc += gcat[g * 30 + k] * Wf[k * ODIM + c];
        z[c] = acc;
        m = fmaxf(m, acc);
    }
    float s = 0.0f;
    for (int c = 0; c < ODIM; ++c) { z[c] = expf(z[c] - m); s += z[c]; }
    float inv = 1.0f / s;
    for (int c = 0; c < ODIM; ++c) out[g * ODIM + c] = z[c] * inv;
}

extern "C" void kernel_launch(void* const* d_in, const int* in_sizes, int n_in,
                              void* d_out, int out_size, void* d_ws, size_t ws_size,
                              hipStream_t stream) {
    const float* features = (const float*)d_in[0];
    const int*   edge     = (const int*)d_in[1];
    const int*   batch    = (const int*)d_in[2];
    const float* W1 = (const float*)d_in[3];
    const float* b1 = (const float*)d_in[4];
    const float* W2 = (const float*)d_in[5];
    const float* b2 = (const float*)d_in[6];
    const float* W3 = (const float*)d_in[7];
    const float* b3 = (const float*)d_in[8];
    const float* Wl1 = (const float*)d_in[9];
    const float* bl1 = (const float*)d_in[10];
    const float* Wl2 = (const float*)d_in[11];
    const float* bl2 = (const float*)d_in[12];
    const float* Wl3 = (const float*)d_in[13];
    const float* bl3 = (const float*)d_in[14];
    const float* Wf = (const float*)d_in[15];
    const float* bf = (const float*)d_in[16];

    const int* src = edge;
    const int* dst = edge + N_EDGES;

    // ---- workspace layout (256B-aligned slabs) ----
    char* p = (char*)d_ws;
    auto alloc = [&](size_t bytes) -> char* {
        char* q = p;
        p += (bytes + 255) & ~(size_t)255;
        return q;
    };
    int*      deg    = (int*)alloc(N_NODES * 4);
    char*     zend   = p;
    float*    sums   = (float*)alloc(3 * NG * F * 4);
    float*    cnt    = (float*)alloc(NG * 4);
    float*    dinv   = (float*)alloc(N_NODES * 4);
    int*      rp     = (int*)alloc((N_NODES + 1) * 4);
    int*      cursor = (int*)alloc(N_NODES * 4);
    int*      bsum   = (int*)alloc(512 * 4);
    int*      gstart = (int*)alloc((NG + 1) * 4);
    float*    gcat   = (float*)alloc(NG * 30 * 4);
    ushort_t* X      = (ushort_t*)alloc((size_t)N_NODES * F * 2);
    ushort_t* H      = (ushort_t*)alloc((size_t)N_NODES * F * 2);
    int*      meta   = (int*)alloc((size_t)N_EDGES * 4);
    ushort_t* Wp1    = (ushort_t*)alloc(INDIM * 64 * 2);
    ushort_t* Wp2    = (ushort_t*)alloc(F * 64 * 2);
    ushort_t* Wp3    = (ushort_t*)alloc(F * 64 * 2);

    const int zeroN = (int)((zend - (char*)deg) / 4);
    hipLaunchKernelGGL(zero_kernel, dim3((zeroN + 255) / 256), dim3(256), 0, stream, (float*)deg, zeroN);
    hipLaunchKernelGGL(deg_kernel, dim3((N_EDGES + 255) / 256), dim3(256), 0, stream, dst, deg);
    hipLaunchKernelGGL(dinv_kernel, dim3((N_NODES + 255) / 256), dim3(256), 0, stream, deg, dinv);
    hipLaunchKernelGGL(cnt_bs_kernel, dim3((NG + 255) / 256), dim3(256), 0, stream, batch, cnt, gstart);
    hipLaunchKernelGGL(scan1_kernel, dim3(NB_SCAN), dim3(256), 0, stream, deg, rp, bsum);
    hipLaunchKernelGGL(scan2_kernel, dim3(1), dim3(512), 0, stream, bsum);
    hipLaunchKernelGGL(scan3_kernel, dim3(NB_SCAN), dim3(256), 0, stream, rp, bsum, cursor);
    hipLaunchKernelGGL(bin_part_kernel, dim3(BIN_BLOCKS), dim3(256), 0, stream, src, dst, cursor, meta);

    // W packs
    hipLaunchKernelGGL((packW_kernel<INDIM>), dim3((INDIM * 64 + 255) / 256), dim3(256), 0, stream, W1, Wp1);
    hipLaunchKernelGGL((packW_kernel<F>), dim3((F * 64 + 255) / 256), dim3(256), 0, stream, W2, Wp2);
    hipLaunchKernelGGL((packW_kernel<F>), dim3((F * 64 + 255) / 256), dim3(256), 0, stream, W3, Wp3);

    const int aggBlocks  = N_NODES / NPB;        // 6250
    const int gemmBlocks = (N_NODES + 63) / 64;  // 1563

    // ---- layer 1 ----
    hipLaunchKernelGGL((gemm_mfma_kernel<INDIM, true>), dim3(gemmBlocks), dim3(256), 0, stream, (const void*)features, Wp1, H);
    hipLaunchKernelGGL(aggregate_kernel, dim3(aggBlocks), dim3(256), 0, stream, H, meta, rp, dinv, b1, X);
    hipLaunchKernelGGL(pool_kernel, dim3(NG), dim3(256), 0, stream, X, gstart, sums + 0 * NG * F);
    // ---- layer 2 ----
    hipLaunchKernelGGL((gemm_mfma_kernel<F, false>), dim3(gemmBlocks), dim3(256), 0, stream, (const void*)X, Wp2, H);
    hipLaunchKernelGGL(aggregate_kernel, dim3(aggBlocks), dim3(256), 0, stream, H, meta, rp, dinv, b2, X);
    hipLaunchKernelGGL(pool_kernel, dim3(NG), dim3(256), 0, stream, X, gstart, sums + 1 * NG * F);
    // ---- layer 3 ----
    hipLaunchKernelGGL((gemm_mfma_kernel<F, false>), dim3(gemmBlocks), dim3(256), 0, stream, (const void*)X, Wp3, H);
    hipLaunchKernelGGL(aggregate_kernel, dim3(aggBlocks), dim3(256), 0, stream, H, meta, rp, dinv, b3, X);
    hipLaunchKernelGGL(pool_kernel, dim3(NG), dim3(256), 0, stream, X, gstart, sums + 2 * NG * F);

    // ---- heads + final ----
    hipLaunchKernelGGL(head_kernel, dim3(NG), dim3(32), 0, stream, sums, cnt,
                       Wl1, bl1, Wl2, bl2, Wl3, bl3, gcat);
    hipLaunchKernelGGL(final_kernel, dim3((NG + 255) / 256), dim3(256), 0, stream, gcat, Wf, bf, (float*)d_out);
}